// Round 4
// baseline (301.979 us; speedup 1.0000x reference)
//
#include <hip/hip_runtime.h>
#include <hip/hip_bf16.h>

typedef __bf16 bf16x8 __attribute__((ext_vector_type(8)));
typedef __bf16 bf16x4 __attribute__((ext_vector_type(4)));
typedef float  f32x4  __attribute__((ext_vector_type(4)));

#define B_SZ    1024
#define COUT_SZ 512
#define K_SZ    32768
#define TM 128
#define TN 128
#define BK 32
#define WPAN (COUT_SZ * BK)   // one k-panel of k-blocked wt

__device__ __forceinline__ void async_copy16(const void* g, void* l) {
  __builtin_amdgcn_global_load_lds(
      (const __attribute__((address_space(1))) unsigned int*)g,
      (__attribute__((address_space(3))) unsigned int*)l, 16, 0, 0);
}

__device__ __forceinline__ void block_barrier() {
  __builtin_amdgcn_sched_barrier(0);
  asm volatile("" ::: "memory");
  __builtin_amdgcn_s_barrier();
  asm volatile("" ::: "memory");
  __builtin_amdgcn_sched_barrier(0);
}

// blocks [0,8192): x fp32 -> xb bf16 (same layout), skipped if xb==nullptr.
// blocks [8192,12288): W fp32 [k][o] -> wt bf16 k-blocked:
//   wt[(k>>5)*WPAN + o*32 + (k&31)]  (a 128o x 32k B-tile = contiguous 8 KB)
__global__ __launch_bounds__(256) void prep_kernel(
    const float* __restrict__ x, __bf16* __restrict__ xb,
    const float* __restrict__ w, __bf16* __restrict__ wt) {
  __shared__ float t[64 * 65];
  if (blockIdx.x < 8192) {
    if (xb == nullptr) return;
    const int lane = threadIdx.x & 63;
    const int wv   = threadIdx.x >> 6;
    const size_t base = (size_t)blockIdx.x * 4096 + wv * 1024 + lane * 4;
#pragma unroll
    for (int i = 0; i < 4; ++i) {
      const size_t off = base + i * 256;
      f32x4 v = *(const f32x4*)(x + off);
      bf16x4 c;
#pragma unroll
      for (int e = 0; e < 4; ++e) c[e] = (__bf16)v[e];
      *(bf16x4*)(xb + off) = c;
    }
    return;
  }
  const int bid = blockIdx.x - 8192;
  const int kb = (bid & 511) * 64;
  const int ob = (bid >> 9) * 64;
  const int tid = threadIdx.x;
  {
    const int o4 = (tid & 15) * 4;
    const int kr = tid >> 4;
    const float* src = w + (size_t)(kb + kr) * COUT_SZ + ob + o4;
#pragma unroll
    for (int i = 0; i < 4; ++i) {
      f32x4 v = *(const f32x4*)(src + (size_t)(16 * i) * COUT_SZ);
      *(f32x4*)&t[(kr + 16 * i) * 65 + o4] = v;
    }
  }
  __syncthreads();
  {
    const int orow = tid >> 3;
    const int k8   = (tid & 7) * 8;
#pragma unroll
    for (int j = 0; j < 2; ++j) {
      const int o = orow + 32 * j;
      bf16x8 pk;
#pragma unroll
      for (int e = 0; e < 8; ++e) pk[e] = (__bf16)t[(k8 + e) * 65 + o];
      *(bf16x8*)(wt + (size_t)((kb + k8) >> 5) * WPAN
                 + (size_t)(ob + o) * BK + (k8 & 31)) = pk;
    }
  }
}

// Split-K GEMM. DMA_A=true: both operands via global_load_lds, counted
// vmcnt(4), zero cvt in loop. DMA_A=false: fallback (workspace too small for
// xb), reg-staged fp32 A as in the proven R1 kernel. LDS [2][128][32] bf16
// per operand, linear: b128 frag reads at row*64 + q*16 hit the wave64 bank
// floor (8 lanes per 4-bank span, all banks even). Block map: z = lin % S
// -> XCD = z%8; all 32 out-tiles of a z share one XCD L2.
template <bool DMA_A>
__global__ __launch_bounds__(256, 4)
void gemm_t(const float* __restrict__ xf, const __bf16* __restrict__ xb,
            const __bf16* __restrict__ wt, __bf16* __restrict__ dst,
            int kchunk, int S) {
  __shared__ __bf16 As[2][TM * BK];
  __shared__ __bf16 Bs[2][TN * BK];

  const int lin = blockIdx.x;
  const int z = lin % S;
  const int t = lin / S;
  const int m0 = (t & 7) * TM;
  const int n0 = (t >> 3) * TN;
  const int tid  = threadIdx.x;
  const int w    = tid >> 6;
  const int lane = tid & 63;
  const int kbase = z * kchunk;

  const int sR = lane >> 2;
  const int sC = lane & 3;
  // A geometry (DMA path)
  const __bf16* ag0 = xb + (size_t)(m0 + w * 32 + sR) * K_SZ + kbase + sC * 8;
  const __bf16* ag1 = ag0 + (size_t)16 * K_SZ;
  // A geometry (fallback reg-staged path)
  const int ar = tid >> 1;
  const int ah = tid & 1;
  const float* agf = xf + (size_t)(m0 + ar) * K_SZ + kbase + ah * 16;
  const int awOff = ar * BK + ah * 16;
  // B geometry
  const __bf16* bg0 = wt + (size_t)(kbase >> 5) * WPAN
                    + (size_t)(n0 + w * 32 + sR) * BK + sC * 8;
  const __bf16* bg1 = bg0 + 16 * BK;
  const int L0 = (w * 32) * BK, L1 = L0 + 16 * BK;

  const int lm = lane & 15;
  const int q  = lane >> 4;
  const int wm = (w & 1) * 64;
  const int wn = (w >> 1) * 64;

  f32x4 acc[4][4];
#pragma unroll
  for (int i = 0; i < 4; ++i)
#pragma unroll
    for (int j = 0; j < 4; ++j) acc[i][j] = (f32x4){0.f, 0.f, 0.f, 0.f};

  f32x4 pa0, pa1, pa2, pa3;
  if constexpr (DMA_A) {
    async_copy16(ag0, &As[0][L0]);
    async_copy16(ag1, &As[0][L1]);
    ag0 += BK; ag1 += BK;
  } else {
    pa0 = *(const f32x4*)(agf);
    pa1 = *(const f32x4*)(agf + 4);
    pa2 = *(const f32x4*)(agf + 8);
    pa3 = *(const f32x4*)(agf + 12);
    agf += BK;
  }
  async_copy16(bg0, &Bs[0][L0]);
  async_copy16(bg1, &Bs[0][L1]);
  bg0 += WPAN; bg1 += WPAN;

  const int niter = kchunk / BK;
  for (int it = 0; it < niter; ++it) {
    const int cur = it & 1;
    if constexpr (!DMA_A) {  // stage A(it) from regs
      __bf16* aw = &As[cur][awOff];
      bf16x4 c0, c1, c2, c3;
#pragma unroll
      for (int e = 0; e < 4; ++e) {
        c0[e] = (__bf16)pa0[e]; c1[e] = (__bf16)pa1[e];
        c2[e] = (__bf16)pa2[e]; c3[e] = (__bf16)pa3[e];
      }
      *(bf16x4*)(aw) = c0; *(bf16x4*)(aw + 4) = c1;
      *(bf16x4*)(aw + 8) = c2; *(bf16x4*)(aw + 12) = c3;
    }
    if (it + 1 < niter) {
      const int nxt = cur ^ 1;
      if constexpr (DMA_A) {
        async_copy16(ag0, &As[nxt][L0]);
        async_copy16(ag1, &As[nxt][L1]);
        ag0 += BK; ag1 += BK;
      } else {
        pa0 = *(const f32x4*)(agf);
        pa1 = *(const f32x4*)(agf + 4);
        pa2 = *(const f32x4*)(agf + 8);
        pa3 = *(const f32x4*)(agf + 12);
        agf += BK;
      }
      async_copy16(bg0, &Bs[nxt][L0]);
      async_copy16(bg1, &Bs[nxt][L1]);
      bg0 += WPAN; bg1 += WPAN;
      if constexpr (DMA_A)
        asm volatile("s_waitcnt vmcnt(4)" ::: "memory");
      else
        asm volatile("s_waitcnt vmcnt(6) lgkmcnt(0)" ::: "memory");
    } else {
      asm volatile("s_waitcnt vmcnt(0) lgkmcnt(0)" ::: "memory");
    }
    block_barrier();  // tiles[cur] valid

    bf16x8 af[4];
#pragma unroll
    for (int i = 0; i < 4; ++i)
      af[i] = *(const bf16x8*)&As[cur][(wm + i * 16 + lm) * BK + q * 8];
    __builtin_amdgcn_s_setprio(1);
#pragma unroll
    for (int j = 0; j < 4; ++j) {
      bf16x8 bfr = *(const bf16x8*)&Bs[cur][(wn + j * 16 + lm) * BK + q * 8];
#pragma unroll
      for (int i = 0; i < 4; ++i)
        acc[i][j] = __builtin_amdgcn_mfma_f32_16x16x32_bf16(af[i], bfr,
                                                            acc[i][j], 0, 0, 0);
    }
    __builtin_amdgcn_s_setprio(0);
    block_barrier();  // reads of [cur] retired; t+1 may restage it
  }

  __bf16* outp = dst + (size_t)z * (B_SZ * COUT_SZ)
               + (size_t)(m0 + wm + q * 4) * COUT_SZ + (n0 + wn + lm);
#pragma unroll
  for (int i = 0; i < 4; ++i) {
#pragma unroll
    for (int r = 0; r < 4; ++r) {
      __bf16* o2 = outp + (size_t)(i * 16 + r) * COUT_SZ;
#pragma unroll
      for (int j = 0; j < 4; ++j) o2[j * 16] = (__bf16)acc[i][j][r];
    }
  }
}

__global__ __launch_bounds__(256) void reduce_kernel(
    const __bf16* __restrict__ p, float* __restrict__ out, int S, float scale) {
  const size_t i = ((size_t)blockIdx.x * 256 + threadIdx.x) * 4;
  float s0 = 0.f, s1 = 0.f, s2 = 0.f, s3 = 0.f;
#pragma unroll 4
  for (int zz = 0; zz < S; ++zz) {
    bf16x4 v = *(const bf16x4*)(p + (size_t)zz * (B_SZ * COUT_SZ) + i);
    s0 += (float)v[0]; s1 += (float)v[1];
    s2 += (float)v[2]; s3 += (float)v[3];
  }
  f32x4 o = {s0 * scale, s1 * scale, s2 * scale, s3 * scale};
  *(f32x4*)(out + i) = o;
}

extern "C" void kernel_launch(void* const* d_in, const int* in_sizes, int n_in,
                              void* d_out, int out_size, void* d_ws, size_t ws_size,
                              hipStream_t stream) {
  const float* x = (const float*)d_in[0];
  const float* w = (const float*)d_in[1];
  float* out = (float*)d_out;

  const size_t xbB    = (size_t)B_SZ * K_SZ * sizeof(__bf16);      // 67.1 MB
  const size_t wtB    = (size_t)COUT_SZ * K_SZ * sizeof(__bf16);   // 33.5 MB
  const size_t sliceB = (size_t)B_SZ * COUT_SZ * sizeof(__bf16);   // 1 MB
  const float scale = 0.04419417382415922f;  // 1/sqrt(512)

  const bool use_xb = (xbB + wtB + sliceB) <= ws_size;

  if (use_xb) {
    __bf16* xb = (__bf16*)d_ws;
    __bf16* wt = (__bf16*)((char*)d_ws + xbB);
    __bf16* partials = (__bf16*)((char*)d_ws + xbB + wtB);
    int S = 32;
    while (S > 1 && xbB + wtB + (size_t)S * sliceB > ws_size) S >>= 1;
    hipLaunchKernelGGL(prep_kernel, dim3(12288), dim3(256), 0, stream,
                       x, xb, w, wt);
    hipLaunchKernelGGL((gemm_t<true>), dim3(32 * S), dim3(256), 0, stream,
                       x, xb, wt, partials, K_SZ / S, S);
    hipLaunchKernelGGL(reduce_kernel, dim3(B_SZ * COUT_SZ / (256 * 4)),
                       dim3(256), 0, stream, partials, out, S, scale);
  } else {
    __bf16* wt = (__bf16*)d_ws;
    __bf16* partials = (__bf16*)((char*)d_ws + wtB);
    int S = 32;
    while (S > 1 && wtB + (size_t)S * sliceB > ws_size) S >>= 1;
    hipLaunchKernelGGL(prep_kernel, dim3(12288), dim3(256), 0, stream,
                       x, (__bf16*)nullptr, w, wt);
    hipLaunchKernelGGL((gemm_t<false>), dim3(32 * S), dim3(256), 0, stream,
                       x, (const __bf16*)nullptr, wt, partials, K_SZ / S, S);
    hipLaunchKernelGGL(reduce_kernel, dim3(B_SZ * COUT_SZ / (256 * 4)),
                       dim3(256), 0, stream, partials, out, S, scale);
  }
}

// Round 5
// 296.979 us; speedup vs baseline: 1.0168x; 1.0168x over previous
//
#include <hip/hip_runtime.h>
#include <hip/hip_bf16.h>

typedef __bf16 bf16x8 __attribute__((ext_vector_type(8)));
typedef __bf16 bf16x4 __attribute__((ext_vector_type(4)));
typedef float  f32x4  __attribute__((ext_vector_type(4)));

#define B_SZ    1024
#define COUT_SZ 512
#define K_SZ    32768
#define TM 128
#define TN 128
#define BK 32
#define WPAN (COUT_SZ * BK)   // one k-panel of k-blocked wt

__device__ __forceinline__ void async_copy16(const void* g, void* l) {
  __builtin_amdgcn_global_load_lds(
      (const __attribute__((address_space(1))) unsigned int*)g,
      (__attribute__((address_space(3))) unsigned int*)l, 16, 0, 0);
}

__device__ __forceinline__ void block_barrier() {
  __builtin_amdgcn_sched_barrier(0);
  asm volatile("" ::: "memory");
  __builtin_amdgcn_s_barrier();
  asm volatile("" ::: "memory");
  __builtin_amdgcn_sched_barrier(0);
}

// blocks [0,4096): x fp32 -> xb bf16 (same layout), 16B stores, 32 elem/thr.
//   Skipped if xb == nullptr (fallback path).
// blocks [4096,8192): W fp32 [k][o] -> wt bf16 k-blocked:
//   wt[(k>>5)*WPAN + o*32 + (k&31)]  (a 128o x 32k B-tile = contiguous 8 KB)
__global__ __launch_bounds__(256) void prep_kernel(
    const float* __restrict__ x, __bf16* __restrict__ xb,
    const float* __restrict__ w, __bf16* __restrict__ wt) {
  __shared__ float t[64 * 65];
  if (blockIdx.x < 4096) {
    if (xb == nullptr) return;
    const size_t b0 = (size_t)blockIdx.x * 8192 + threadIdx.x * 8;
#pragma unroll
    for (int i = 0; i < 4; ++i) {
      const size_t off = b0 + (size_t)i * 2048;
      f32x4 v0 = *(const f32x4*)(x + off);
      f32x4 v1 = *(const f32x4*)(x + off + 4);
      bf16x8 c;
#pragma unroll
      for (int e = 0; e < 4; ++e) {
        c[e]     = (__bf16)v0[e];
        c[e + 4] = (__bf16)v1[e];
      }
      *(bf16x8*)(xb + off) = c;
    }
    return;
  }
  const int bid = blockIdx.x - 4096;
  const int kb = (bid & 511) * 64;
  const int ob = (bid >> 9) * 64;
  const int tid = threadIdx.x;
  {
    const int o4 = (tid & 15) * 4;
    const int kr = tid >> 4;
    const float* src = w + (size_t)(kb + kr) * COUT_SZ + ob + o4;
#pragma unroll
    for (int i = 0; i < 4; ++i) {
      f32x4 v = *(const f32x4*)(src + (size_t)(16 * i) * COUT_SZ);
      *(f32x4*)&t[(kr + 16 * i) * 65 + o4] = v;
    }
  }
  __syncthreads();
  {
    const int orow = tid >> 3;
    const int k8   = (tid & 7) * 8;
#pragma unroll
    for (int j = 0; j < 2; ++j) {
      const int o = orow + 32 * j;
      bf16x8 pk;
#pragma unroll
      for (int e = 0; e < 8; ++e) pk[e] = (__bf16)t[(k8 + e) * 65 + o];
      *(bf16x8*)(wt + (size_t)((kb + k8) >> 5) * WPAN
                 + (size_t)(ob + o) * BK + (k8 & 31)) = pk;
    }
  }
}

// Split-K GEMM (unchanged from the passing R4 version). DMA_A=true: both
// operands via global_load_lds, counted vmcnt(4), zero cvt in loop.
// DMA_A=false: fallback (workspace too small for xb), reg-staged fp32 A.
// LDS [2][128][32] bf16 per operand, linear: b128 frag reads hit the wave64
// bank floor. Block map: z = lin % S -> XCD = z%8.
template <bool DMA_A>
__global__ __launch_bounds__(256, 4)
void gemm_t(const float* __restrict__ xf, const __bf16* __restrict__ xb,
            const __bf16* __restrict__ wt, __bf16* __restrict__ dst,
            int kchunk, int S) {
  __shared__ __bf16 As[2][TM * BK];
  __shared__ __bf16 Bs[2][TN * BK];

  const int lin = blockIdx.x;
  const int z = lin % S;
  const int t = lin / S;
  const int m0 = (t & 7) * TM;
  const int n0 = (t >> 3) * TN;
  const int tid  = threadIdx.x;
  const int w    = tid >> 6;
  const int lane = tid & 63;
  const int kbase = z * kchunk;

  const int sR = lane >> 2;
  const int sC = lane & 3;
  const __bf16* ag0 = xb + (size_t)(m0 + w * 32 + sR) * K_SZ + kbase + sC * 8;
  const __bf16* ag1 = ag0 + (size_t)16 * K_SZ;
  const int ar = tid >> 1;
  const int ah = tid & 1;
  const float* agf = xf + (size_t)(m0 + ar) * K_SZ + kbase + ah * 16;
  const int awOff = ar * BK + ah * 16;
  const __bf16* bg0 = wt + (size_t)(kbase >> 5) * WPAN
                    + (size_t)(n0 + w * 32 + sR) * BK + sC * 8;
  const __bf16* bg1 = bg0 + 16 * BK;
  const int L0 = (w * 32) * BK, L1 = L0 + 16 * BK;

  const int lm = lane & 15;
  const int q  = lane >> 4;
  const int wm = (w & 1) * 64;
  const int wn = (w >> 1) * 64;

  f32x4 acc[4][4];
#pragma unroll
  for (int i = 0; i < 4; ++i)
#pragma unroll
    for (int j = 0; j < 4; ++j) acc[i][j] = (f32x4){0.f, 0.f, 0.f, 0.f};

  f32x4 pa0, pa1, pa2, pa3;
  if constexpr (DMA_A) {
    async_copy16(ag0, &As[0][L0]);
    async_copy16(ag1, &As[0][L1]);
    ag0 += BK; ag1 += BK;
  } else {
    pa0 = *(const f32x4*)(agf);
    pa1 = *(const f32x4*)(agf + 4);
    pa2 = *(const f32x4*)(agf + 8);
    pa3 = *(const f32x4*)(agf + 12);
    agf += BK;
  }
  async_copy16(bg0, &Bs[0][L0]);
  async_copy16(bg1, &Bs[0][L1]);
  bg0 += WPAN; bg1 += WPAN;

  const int niter = kchunk / BK;
  for (int it = 0; it < niter; ++it) {
    const int cur = it & 1;
    if constexpr (!DMA_A) {
      __bf16* aw = &As[cur][awOff];
      bf16x4 c0, c1, c2, c3;
#pragma unroll
      for (int e = 0; e < 4; ++e) {
        c0[e] = (__bf16)pa0[e]; c1[e] = (__bf16)pa1[e];
        c2[e] = (__bf16)pa2[e]; c3[e] = (__bf16)pa3[e];
      }
      *(bf16x4*)(aw) = c0; *(bf16x4*)(aw + 4) = c1;
      *(bf16x4*)(aw + 8) = c2; *(bf16x4*)(aw + 12) = c3;
    }
    if (it + 1 < niter) {
      const int nxt = cur ^ 1;
      if constexpr (DMA_A) {
        async_copy16(ag0, &As[nxt][L0]);
        async_copy16(ag1, &As[nxt][L1]);
        ag0 += BK; ag1 += BK;
      } else {
        pa0 = *(const f32x4*)(agf);
        pa1 = *(const f32x4*)(agf + 4);
        pa2 = *(const f32x4*)(agf + 8);
        pa3 = *(const f32x4*)(agf + 12);
        agf += BK;
      }
      async_copy16(bg0, &Bs[nxt][L0]);
      async_copy16(bg1, &Bs[nxt][L1]);
      bg0 += WPAN; bg1 += WPAN;
      if constexpr (DMA_A)
        asm volatile("s_waitcnt vmcnt(4)" ::: "memory");
      else
        asm volatile("s_waitcnt vmcnt(6) lgkmcnt(0)" ::: "memory");
    } else {
      asm volatile("s_waitcnt vmcnt(0) lgkmcnt(0)" ::: "memory");
    }
    block_barrier();

    bf16x8 af[4];
#pragma unroll
    for (int i = 0; i < 4; ++i)
      af[i] = *(const bf16x8*)&As[cur][(wm + i * 16 + lm) * BK + q * 8];
    __builtin_amdgcn_s_setprio(1);
#pragma unroll
    for (int j = 0; j < 4; ++j) {
      bf16x8 bfr = *(const bf16x8*)&Bs[cur][(wn + j * 16 + lm) * BK + q * 8];
#pragma unroll
      for (int i = 0; i < 4; ++i)
        acc[i][j] = __builtin_amdgcn_mfma_f32_16x16x32_bf16(af[i], bfr,
                                                            acc[i][j], 0, 0, 0);
    }
    __builtin_amdgcn_s_setprio(0);
    block_barrier();
  }

  __bf16* outp = dst + (size_t)z * (B_SZ * COUT_SZ)
               + (size_t)(m0 + wm + q * 4) * COUT_SZ + (n0 + wn + lm);
#pragma unroll
  for (int i = 0; i < 4; ++i) {
#pragma unroll
    for (int r = 0; r < 4; ++r) {
      __bf16* o2 = outp + (size_t)(i * 16 + r) * COUT_SZ;
#pragma unroll
      for (int j = 0; j < 4; ++j) o2[j * 16] = (__bf16)acc[i][j][r];
    }
  }
}

__global__ __launch_bounds__(256) void reduce_kernel(
    const __bf16* __restrict__ p, float* __restrict__ out, int S, float scale) {
  const size_t i = ((size_t)blockIdx.x * 256 + threadIdx.x) * 4;
  float s0 = 0.f, s1 = 0.f, s2 = 0.f, s3 = 0.f;
#pragma unroll 8
  for (int zz = 0; zz < S; ++zz) {
    bf16x4 v = *(const bf16x4*)(p + (size_t)zz * (B_SZ * COUT_SZ) + i);
    s0 += (float)v[0]; s1 += (float)v[1];
    s2 += (float)v[2]; s3 += (float)v[3];
  }
  f32x4 o = {s0 * scale, s1 * scale, s2 * scale, s3 * scale};
  *(f32x4*)(out + i) = o;
}

extern "C" void kernel_launch(void* const* d_in, const int* in_sizes, int n_in,
                              void* d_out, int out_size, void* d_ws, size_t ws_size,
                              hipStream_t stream) {
  const float* x = (const float*)d_in[0];
  const float* w = (const float*)d_in[1];
  float* out = (float*)d_out;

  const size_t xbB    = (size_t)B_SZ * K_SZ * sizeof(__bf16);      // 67.1 MB
  const size_t wtB    = (size_t)COUT_SZ * K_SZ * sizeof(__bf16);   // 33.5 MB
  const size_t sliceB = (size_t)B_SZ * COUT_SZ * sizeof(__bf16);   // 1 MB
  const float scale = 0.04419417382415922f;  // 1/sqrt(512)

  const bool use_xb = (xbB + wtB + sliceB) <= ws_size;

  if (use_xb) {
    __bf16* xb = (__bf16*)d_ws;
    __bf16* wt = (__bf16*)((char*)d_ws + xbB);
    __bf16* partials = (__bf16*)((char*)d_ws + xbB + wtB);
    int S = 32;
    while (S > 1 && xbB + wtB + (size_t)S * sliceB > ws_size) S >>= 1;
    hipLaunchKernelGGL(prep_kernel, dim3(8192), dim3(256), 0, stream,
                       x, xb, w, wt);
    hipLaunchKernelGGL((gemm_t<true>), dim3(32 * S), dim3(256), 0, stream,
                       x, xb, wt, partials, K_SZ / S, S);
    hipLaunchKernelGGL(reduce_kernel, dim3(B_SZ * COUT_SZ / (256 * 4)),
                       dim3(256), 0, stream, partials, out, S, scale);
  } else {
    __bf16* wt = (__bf16*)d_ws;
    __bf16* partials = (__bf16*)((char*)d_ws + wtB);
    int S = 32;
    while (S > 1 && wtB + (size_t)S * sliceB > ws_size) S >>= 1;
    hipLaunchKernelGGL(prep_kernel, dim3(8192), dim3(256), 0, stream,
                       x, (__bf16*)nullptr, w, wt);
    hipLaunchKernelGGL((gemm_t<false>), dim3(32 * S), dim3(256), 0, stream,
                       x, (const __bf16*)nullptr, wt, partials, K_SZ / S, S);
    hipLaunchKernelGGL(reduce_kernel, dim3(B_SZ * COUT_SZ / (256 * 4)),
                       dim3(256), 0, stream, partials, out, S, scale);
  }
}

// Round 6
// 283.453 us; speedup vs baseline: 1.0654x; 1.0477x over previous
//
#include <hip/hip_runtime.h>
#include <hip/hip_bf16.h>

typedef __bf16 bf16x8 __attribute__((ext_vector_type(8)));
typedef __bf16 bf16x4 __attribute__((ext_vector_type(4)));
typedef float  f32x4  __attribute__((ext_vector_type(4)));

#define B_SZ    1024
#define COUT_SZ 512
#define K_SZ    32768
#define TM 128
#define TN 128
#define BK 32
#define APITCH 36             // 72 B rows: A write b64 + frag b64 reads at bank
                              // floor, 8 B aligned for all rows (R1-proven)
#define WPAN (COUT_SZ * BK)   // one k-panel of k-blocked wt

__device__ __forceinline__ void async_copy16(const void* g, void* l) {
  __builtin_amdgcn_global_load_lds(
      (const __attribute__((address_space(1))) unsigned int*)g,
      (__attribute__((address_space(3))) unsigned int*)l, 16, 0, 0);
}

__device__ __forceinline__ void block_barrier() {
  __builtin_amdgcn_sched_barrier(0);
  asm volatile("" ::: "memory");
  __builtin_amdgcn_s_barrier();
  asm volatile("" ::: "memory");
  __builtin_amdgcn_sched_barrier(0);
}

// W fp32 [k][o] -> wt bf16 k-blocked: wt[(k>>5)*WPAN + o*32 + (k&31)]
// (a 128o x 32k B-tile = contiguous 8 KB for global_load_lds).
// xcvt phase REMOVED: gemm now converts x on the fly, killing the 134 MB
// xb write+read round trip that kept prep at 93 us.
__global__ __launch_bounds__(256) void prep_kernel(
    const float* __restrict__ w, __bf16* __restrict__ wt) {
  __shared__ float t[64 * 65];
  const int kb = (blockIdx.x & 511) * 64;
  const int ob = (blockIdx.x >> 9) * 64;
  const int tid = threadIdx.x;
  {
    const int o4 = (tid & 15) * 4;
    const int kr = tid >> 4;
    const float* src = w + (size_t)(kb + kr) * COUT_SZ + ob + o4;
#pragma unroll
    for (int i = 0; i < 4; ++i) {
      f32x4 v = *(const f32x4*)(src + (size_t)(16 * i) * COUT_SZ);
      *(f32x4*)&t[(kr + 16 * i) * 65 + o4] = v;
    }
  }
  __syncthreads();
  {
    const int orow = tid >> 3;
    const int k8   = (tid & 7) * 8;
#pragma unroll
    for (int j = 0; j < 2; ++j) {
      const int o = orow + 32 * j;
      bf16x8 pk;
#pragma unroll
      for (int e = 0; e < 8; ++e) pk[e] = (__bf16)t[(k8 + e) * 65 + o];
      *(bf16x8*)(wt + (size_t)((kb + k8) >> 5) * WPAN
                 + (size_t)(ob + o) * BK + (k8 & 31)) = pk;
    }
  }
}

__device__ __forceinline__ void stageA(__bf16* aw, f32x4 p0, f32x4 p1,
                                       f32x4 p2, f32x4 p3) {
  bf16x4 c0, c1, c2, c3;
#pragma unroll
  for (int e = 0; e < 4; ++e) {
    c0[e] = (__bf16)p0[e]; c1[e] = (__bf16)p1[e];
    c2[e] = (__bf16)p2[e]; c3[e] = (__bf16)p3[e];
  }
  *(bf16x4*)(aw)      = c0;
  *(bf16x4*)(aw + 4)  = c1;
  *(bf16x4*)(aw + 8)  = c2;
  *(bf16x4*)(aw + 12) = c3;
}

// Split-K GEMM, fused x-conversion, post-barrier staging schedule.
// A: x fp32 -> regs (loaded 1 iter ahead) -> cvt+ds_write AFTER bar4 into
//    As[nxt], overlapping this iter's MFMA (R1 put this between barriers =
//    serial lockstep region = its 95 us).
// B: global_load_lds from k-blocked wt into Bs[nxt], issued right after bar4.
// Hazards: buffers written post-bar4(t) were last read before bar7(t-1),
// which every wave passed before reaching bar4(t). Pre-bar4 wait is
// vmcnt(0)+lgkmcnt(0) but everything outstanding is ~1 MFMA-phase old; the
// residual B latency is hidden by 4 co-resident blocks/CU.
// LDS: As[2][128*36] (18 KB) + Bs[2][128*32] (16 KB) = 34 KB -> 4 blocks/CU.
// Block map lin = z + S*t: XCD = z%8 (S=32 -> all 32 out-tiles of a z-group
// share one XCD's L2).
__global__ __launch_bounds__(256, 4)
void gemm_kernel(const float* __restrict__ x, const __bf16* __restrict__ wt,
                 __bf16* __restrict__ dst, int kchunk, int S) {
  __shared__ __bf16 As[2][TM * APITCH];
  __shared__ __bf16 Bs[2][TN * BK];

  const int lin = blockIdx.x;
  const int z = lin % S;
  const int t = lin / S;
  const int m0 = (t & 7) * TM;
  const int n0 = (t >> 3) * TN;
  const int tid  = threadIdx.x;
  const int w    = tid >> 6;
  const int lane = tid & 63;
  const int kbase = z * kchunk;

  // A: thread -> row tid>>1, k-half (tid&1)*16 (fp32, 64 B per thread)
  const int ar = tid >> 1;
  const int ah = tid & 1;
  const float* ag = x + (size_t)(m0 + ar) * K_SZ + kbase + ah * 16;
  const int awOff = ar * APITCH + ah * 16;
  // B: wave w stages rows [32w,32w+32); lane l -> row l>>2, chunk l&3 of a
  // contiguous 1 KB source region (k-blocked wt)
  const int sR = lane >> 2;
  const int sC = lane & 3;
  const __bf16* bg0 = wt + (size_t)(kbase >> 5) * WPAN
                    + (size_t)(n0 + w * 32 + sR) * BK + sC * 8;
  const __bf16* bg1 = bg0 + 16 * BK;
  const int L0 = (w * 32) * BK, L1 = L0 + 16 * BK;

  const int lm = lane & 15;
  const int q  = lane >> 4;
  const int wm = (w & 1) * 64;
  const int wn = (w >> 1) * 64;

  f32x4 acc[4][4];
#pragma unroll
  for (int i = 0; i < 4; ++i)
#pragma unroll
    for (int j = 0; j < 4; ++j) acc[i][j] = (f32x4){0.f, 0.f, 0.f, 0.f};

  // prologue: A(0)->regs, B(0) DMA, cvt A(0)->As[0], A(1)->regs
  f32x4 pa0 = *(const f32x4*)(ag);
  f32x4 pa1 = *(const f32x4*)(ag + 4);
  f32x4 pa2 = *(const f32x4*)(ag + 8);
  f32x4 pa3 = *(const f32x4*)(ag + 12);
  ag += BK;
  async_copy16(bg0, &Bs[0][L0]);
  async_copy16(bg1, &Bs[0][L1]);
  bg0 += WPAN; bg1 += WPAN;
  stageA(&As[0][awOff], pa0, pa1, pa2, pa3);  // waits pa; B(0) stays in flight
  pa0 = *(const f32x4*)(ag);
  pa1 = *(const f32x4*)(ag + 4);
  pa2 = *(const f32x4*)(ag + 8);
  pa3 = *(const f32x4*)(ag + 12);
  ag += BK;

  const int niter = kchunk / BK;
  for (int it = 0; it < niter; ++it) {
    const int cur = it & 1;
    const int nxt = cur ^ 1;
    // everything outstanding is >= 1 phase old (B(it), pa(it+1), A(it) writes)
    asm volatile("s_waitcnt vmcnt(0) lgkmcnt(0)" ::: "memory");
    block_barrier();  // tiles[cur] valid for all waves

    if (it + 1 < niter) {  // B(it+1): earliest possible issue
      async_copy16(bg0, &Bs[nxt][L0]);
      async_copy16(bg1, &Bs[nxt][L1]);
      bg0 += WPAN; bg1 += WPAN;
    }

    bf16x8 af[4];
#pragma unroll
    for (int i = 0; i < 4; ++i) {
      const __bf16* arow = &As[cur][(wm + i * 16 + lm) * APITCH + q * 8];
      bf16x4 lo = *(const bf16x4*)arow;
      bf16x4 hi = *(const bf16x4*)(arow + 4);
      bf16x8 a;
#pragma unroll
      for (int e = 0; e < 4; ++e) { a[e] = lo[e]; a[e + 4] = hi[e]; }
      af[i] = a;
    }

    if (it + 1 < niter)  // cvt A(it+1) -> As[nxt], overlaps MFMA below
      stageA(&As[nxt][awOff], pa0, pa1, pa2, pa3);
    if (it + 2 < niter) {  // A(it+2) -> regs
      pa0 = *(const f32x4*)(ag);
      pa1 = *(const f32x4*)(ag + 4);
      pa2 = *(const f32x4*)(ag + 8);
      pa3 = *(const f32x4*)(ag + 12);
      ag += BK;
    }

    __builtin_amdgcn_s_setprio(1);
#pragma unroll
    for (int j = 0; j < 4; ++j) {
      bf16x8 bfr = *(const bf16x8*)&Bs[cur][(wn + j * 16 + lm) * BK + q * 8];
#pragma unroll
      for (int i = 0; i < 4; ++i)
        acc[i][j] = __builtin_amdgcn_mfma_f32_16x16x32_bf16(af[i], bfr,
                                                            acc[i][j], 0, 0, 0);
    }
    __builtin_amdgcn_s_setprio(0);
    block_barrier();  // reads of [cur] retired; next iter may restage it
  }

  // epilogue -> bf16 partials. C/D layout col=lane&15, row=(lane>>4)*4+reg.
  __bf16* outp = dst + (size_t)z * (B_SZ * COUT_SZ)
               + (size_t)(m0 + wm + q * 4) * COUT_SZ + (n0 + wn + lm);
#pragma unroll
  for (int i = 0; i < 4; ++i) {
#pragma unroll
    for (int r = 0; r < 4; ++r) {
      __bf16* o2 = outp + (size_t)(i * 16 + r) * COUT_SZ;
#pragma unroll
      for (int j = 0; j < 4; ++j) o2[j * 16] = (__bf16)acc[i][j][r];
    }
  }
}

__global__ __launch_bounds__(256) void reduce_kernel(
    const __bf16* __restrict__ p, float* __restrict__ out, int S, float scale) {
  const size_t i = ((size_t)blockIdx.x * 256 + threadIdx.x) * 4;
  float s0 = 0.f, s1 = 0.f, s2 = 0.f, s3 = 0.f;
#pragma unroll 8
  for (int zz = 0; zz < S; ++zz) {
    bf16x4 v = *(const bf16x4*)(p + (size_t)zz * (B_SZ * COUT_SZ) + i);
    s0 += (float)v[0]; s1 += (float)v[1];
    s2 += (float)v[2]; s3 += (float)v[3];
  }
  f32x4 o = {s0 * scale, s1 * scale, s2 * scale, s3 * scale};
  *(f32x4*)(out + i) = o;
}

extern "C" void kernel_launch(void* const* d_in, const int* in_sizes, int n_in,
                              void* d_out, int out_size, void* d_ws, size_t ws_size,
                              hipStream_t stream) {
  const float* x = (const float*)d_in[0];
  const float* w = (const float*)d_in[1];
  float* out = (float*)d_out;

  const size_t wtB    = (size_t)COUT_SZ * K_SZ * sizeof(__bf16);   // 33.5 MB
  const size_t sliceB = (size_t)B_SZ * COUT_SZ * sizeof(__bf16);   // 1 MB
  const float scale = 0.04419417382415922f;  // 1/sqrt(512)

  __bf16* wt = (__bf16*)d_ws;
  __bf16* partials = (__bf16*)((char*)d_ws + wtB);

  int S = 32;  // grid 1024 = 4 blocks/CU fully co-resident; kchunk 1024
  while (S > 1 && wtB + (size_t)S * sliceB > ws_size) S >>= 1;

  hipLaunchKernelGGL(prep_kernel, dim3((K_SZ / 64) * (COUT_SZ / 64)), dim3(256),
                     0, stream, w, wt);
  hipLaunchKernelGGL(gemm_kernel, dim3(32 * S), dim3(256), 0, stream,
                     x, wt, partials, K_SZ / S, S);
  hipLaunchKernelGGL(reduce_kernel, dim3(B_SZ * COUT_SZ / (256 * 4)),
                     dim3(256), 0, stream, partials, out, S, scale);
}